// Round 1
// baseline (319.958 us; speedup 1.0000x reference)
//
#include <hip/hip_runtime.h>
#include <math.h>

// PostProcess: B=16 images, Q=2048 queries, C=2 classes.
//  scores = max softmax prob; labels = argmax; valid = (label==0 && score>=0.7)
//  boxes: cxcywh -> xyxy, scaled by (w,h,w,h)
//  per-image greedy NMS (IoU>0.5) over valid boxes sorted by score desc
//  outputs (concat, float32): scores_out[B*Q], boxes_out[B*Q*4] (trunc-to-int vals), keep[B*Q]

#define QN 2048
#define BLOCK 256

__global__ __launch_bounds__(BLOCK) void postprocess_kernel(
    const float* __restrict__ logits,   // [B,Q,2]
    const float* __restrict__ pboxes,   // [B,Q,4]
    const int* __restrict__ img_h_p,
    const int* __restrict__ img_w_p,
    float* __restrict__ out,            // scores | boxes | keep (all float32)
    int B)
{
    __shared__ float sbx[QN][4];                 // 32 KB  scaled xyxy, orig order
    __shared__ unsigned long long skey[QN];      // 16 KB  sort keys
    __shared__ unsigned short sidx[QN];          //  4 KB  sorted -> orig idx
    __shared__ unsigned char ssupp[QN];          //  2 KB  suppressed flag (sorted order)
    __shared__ unsigned char skorig[QN];         //  2 KB  keep flag (orig order)
    __shared__ int sM;

    const int b   = blockIdx.x;
    const int tid = threadIdx.x;
    const float sw = (float)(*img_w_p);
    const float sh = (float)(*img_h_p);

    if (tid == 0) sM = 0;
    __syncthreads();

    // ---- Phase 1: score/valid/boxes ----
    int local_valid = 0;
    for (int q = tid; q < QN; q += BLOCK) {
        const long base = (long)(b * QN + q);
        float l0 = logits[base * 2 + 0];
        float l1 = logits[base * 2 + 1];
        float mx = fmaxf(l0, l1);
        float mn = fminf(l0, l1);
        float e  = expf(mn - mx);                 // exp(0)=1 exactly for the max lane
        float score = 1.0f / (1.0f + e);          // = max softmax prob
        bool  label0 = (l0 >= l1);                // argmax tie -> index 0
        bool  valid  = label0 && (score >= 0.7f);

        float cx = pboxes[base * 4 + 0];
        float cy = pboxes[base * 4 + 1];
        float w  = pboxes[base * 4 + 2];
        float h  = pboxes[base * 4 + 3];
        sbx[q][0] = (cx - 0.5f * w) * sw;
        sbx[q][1] = (cy - 0.5f * h) * sh;
        sbx[q][2] = (cx + 0.5f * w) * sw;
        sbx[q][3] = (cy + 0.5f * h) * sh;

        // key: ascending sort == score desc (ties: lower idx first); invalid -> end
        unsigned int sbits = valid ? __float_as_uint(score) : 0u;
        skey[q] = ((unsigned long long)(~sbits) << 32) | (unsigned int)q;
        ssupp[q]  = 0;
        skorig[q] = 0;
        if (valid) local_valid++;
    }
    atomicAdd(&sM, local_valid);
    __syncthreads();
    const int M = sM;

    // ---- Phase 2: bitonic ascending sort of skey (2048 u64) ----
    for (unsigned k = 2; k <= QN; k <<= 1) {
        for (unsigned j = k >> 1; j > 0; j >>= 1) {
            __syncthreads();
            for (unsigned i = tid; i < QN; i += BLOCK) {
                unsigned p = i ^ j;
                if (p > i) {
                    unsigned long long a = skey[i];
                    unsigned long long c = skey[p];
                    bool up = ((i & k) == 0);
                    if ((a > c) == up) { skey[i] = c; skey[p] = a; }
                }
            }
        }
    }
    __syncthreads();
    for (int i = tid; i < QN; i += BLOCK)
        sidx[i] = (unsigned short)(unsigned int)skey[i];
    __syncthreads();

    // ---- Phase 3: greedy NMS (sequential over sorted valid boxes) ----
    for (int i = 0; i < M; ++i) {
        __syncthreads();                       // make ssupp[i] from prior iters visible
        if (ssupp[i]) continue;                // uniform read -> uniform branch
        const int ia = sidx[i];
        const float ax1 = sbx[ia][0], ay1 = sbx[ia][1];
        const float ax2 = sbx[ia][2], ay2 = sbx[ia][3];
        const float areaA = fmaxf(ax2 - ax1, 0.0f) * fmaxf(ay2 - ay1, 0.0f);
        for (int jj = i + 1 + tid; jj < M; jj += BLOCK) {
            const int jb = sidx[jj];
            const float bx1 = sbx[jb][0], by1 = sbx[jb][1];
            const float bx2 = sbx[jb][2], by2 = sbx[jb][3];
            float ltx = fmaxf(ax1, bx1), lty = fmaxf(ay1, by1);
            float rbx = fminf(ax2, bx2), rby = fminf(ay2, by2);
            float wx = fmaxf(rbx - ltx, 0.0f), wy = fmaxf(rby - lty, 0.0f);
            float inter = wx * wy;
            float areaB = fmaxf(bx2 - bx1, 0.0f) * fmaxf(by2 - by1, 0.0f);
            float uni = areaA + areaB - inter;     // same op order as reference
            float iou = inter / fmaxf(uni, 1e-9f);
            if (iou > 0.5f) ssupp[jj] = 1;
        }
    }
    __syncthreads();

    // kept (sorted slot s < M, not suppressed) -> orig-order keep flags
    for (int s = tid; s < M; s += BLOCK)
        if (!ssupp[s]) skorig[sidx[s]] = 1;
    __syncthreads();

    // ---- Phase 4: write all outputs (d_out is poisoned every call) ----
    const long BQ = (long)B * QN;
    float* out_scores = out;            // [B*Q]
    float* out_boxes  = out + BQ;       // [B*Q*4]
    float* out_keep   = out + BQ * 5;   // [B*Q]
    for (int q = tid; q < QN; q += BLOCK) {
        const long base = (long)(b * QN + q);
        float l0 = logits[base * 2 + 0];
        float l1 = logits[base * 2 + 1];
        float e  = expf(fminf(l0, l1) - fmaxf(l0, l1));
        float score = 1.0f / (1.0f + e);
        const int kp = skorig[q];
        out_scores[base] = kp ? score : 0.0f;
        out_keep[base]   = kp ? 1.0f : 0.0f;
        float* ob = out_boxes + base * 4;
        ob[0] = kp ? truncf(sbx[q][0]) : 0.0f;
        ob[1] = kp ? truncf(sbx[q][1]) : 0.0f;
        ob[2] = kp ? truncf(sbx[q][2]) : 0.0f;
        ob[3] = kp ? truncf(sbx[q][3]) : 0.0f;
    }
}

extern "C" void kernel_launch(void* const* d_in, const int* in_sizes, int n_in,
                              void* d_out, int out_size, void* d_ws, size_t ws_size,
                              hipStream_t stream) {
    const float* logits = (const float*)d_in[0];
    const float* pboxes = (const float*)d_in[1];
    const int*   img_h  = (const int*)d_in[2];
    const int*   img_w  = (const int*)d_in[3];
    float* out = (float*)d_out;
    const int B = in_sizes[0] / (QN * 2);   // 16

    postprocess_kernel<<<dim3(B), dim3(BLOCK), 0, stream>>>(
        logits, pboxes, img_h, img_w, out, B);
}

// Round 2
// 156.004 us; speedup vs baseline: 2.0510x; 2.0510x over previous
//
#include <hip/hip_runtime.h>
#include <math.h>

// PostProcess: B=16, Q=2048, C=2.
// scores = max softmax; valid = argmax==0 && score>=0.7; boxes cxcywh->xyxy * (w,h,w,h)
// per-image greedy NMS (IoU>0.5, score-desc stable order) -> keep
// out (f32, concat): scores[B*Q] | boxes[B*Q*4] (trunc int vals) | keep[B*Q]

#define QN   2048
#define NTH  1024
#define CAP  768     // fast-path max valid boxes (E[M]=562, sigma~20 -> 10 sigma margin)
#define U32W 24      // u32 words per full matrix row (CAP/32)

__device__ __forceinline__ int ragged_base(int wb) {
    // 64 * sum_{k<wb} (U32W - 2k) = 64 * wb * (U32W + 1 - wb)
    return 64 * wb * (25 - wb);
}

__global__ __launch_bounds__(NTH) void postprocess_kernel(
    const float* __restrict__ logits,   // [B,Q,2]
    const float* __restrict__ pboxes,   // [B,Q,4]
    const int* __restrict__ img_h_p,
    const int* __restrict__ img_w_p,
    float* __restrict__ out,
    int B)
{
    // 39936 B; aliased as u64 skey[2048] (16 KB) during sort, supp-matrix after
    __shared__ __align__(16) unsigned int u_mat[9984];
    __shared__ unsigned short sidx[QN];                       // 4 KB sorted->orig
    __shared__ float sx1[CAP], sy1[CAP], sx2[CAP], sy2[CAP], sar[CAP]; // 15 KB SoA
    __shared__ unsigned char skorig[QN];                      // 2 KB keep (orig order)
    __shared__ unsigned int skmask[U32W];                     // keep bits (sorted order)
    __shared__ int sM;

    const int b   = blockIdx.x;
    const int tid = threadIdx.x;
    const float sw = (float)(*img_w_p);
    const float sh = (float)(*img_h_p);
    unsigned long long* skey = (unsigned long long*)u_mat;

    if (tid == 0) sM = 0;
    __syncthreads();

    // ---- Phase 1: scores -> sort keys ----
    int local_valid = 0;
    for (int q = tid; q < QN; q += NTH) {
        float2 l = ((const float2*)logits)[b * QN + q];
        float mx = fmaxf(l.x, l.y), mn = fminf(l.x, l.y);
        float e = expf(mn - mx);
        float score = 1.0f / (1.0f + e);                // max softmax prob (exact ref order)
        bool valid = (l.x >= l.y) && (score >= 0.7f);   // argmax tie -> class 0
        unsigned sbits = valid ? __float_as_uint(score) : 0u;
        // ascending sort == score desc, idx asc tiebreak (stable); invalid last
        skey[q] = ((unsigned long long)(~sbits) << 32) | (unsigned)q;
        skorig[q] = 0;
        if (valid) local_valid++;
    }
    if (local_valid) atomicAdd(&sM, local_valid);
    __syncthreads();
    const int M = sM;

    // ---- Phase 2: bitonic ascending sort (2048 u64, 1 pair/thread/pass) ----
    for (int k = 2; k <= QN; k <<= 1) {
        for (int j = k >> 1; j > 0; j >>= 1) {
            __syncthreads();
            int i = ((tid & ~(j - 1)) << 1) | (tid & (j - 1));
            int p = i | j;
            bool up = ((i & k) == 0);
            unsigned long long a = skey[i], c2 = skey[p];
            if ((a > c2) == up) { skey[i] = c2; skey[p] = a; }
        }
    }
    __syncthreads();
    for (int s = tid; s < QN; s += NTH) sidx[s] = (unsigned short)(unsigned)skey[s];
    __syncthreads();   // after this, u_mat region is reusable

    if (M <= CAP) {
        // ---- Phase 3a: gather sorted boxes (SoA) + areas ----
        if (tid < CAP) {
            int s = tid;
            float x1 = 0.f, y1 = 0.f, x2 = 0.f, y2 = 0.f, ar = 0.f;
            if (s < M) {
                int q = sidx[s];
                float4 pb = ((const float4*)pboxes)[b * QN + q];
                x1 = (pb.x - 0.5f * pb.z) * sw;
                y1 = (pb.y - 0.5f * pb.w) * sh;
                x2 = (pb.x + 0.5f * pb.z) * sw;
                y2 = (pb.y + 0.5f * pb.w) * sh;
                ar = fmaxf(x2 - x1, 0.f) * fmaxf(y2 - y1, 0.f);
            }
            sx1[s] = x1; sy1[s] = y1; sx2[s] = x2; sy2[s] = y2; sar[s] = ar;
        }
        __syncthreads();

        // ---- Phase 3b: suppression bit matrix (row per wave, 64 IoUs/ballot) ----
        const int W64 = (M + 63) >> 6;
        const int wave = tid >> 6, lane = tid & 63, nw = NTH >> 6;
        for (int i = wave; i < M; i += nw) {
            float ax1 = sx1[i], ay1 = sy1[i], ax2 = sx2[i], ay2 = sy2[i];
            float areaA = sar[i];
            int wb = i >> 6;
            int rl = U32W - 2 * wb;
            int rbase = ragged_base(wb) + (i & 63) * rl;
            for (int w = wb; w < W64; ++w) {
                int j = (w << 6) | lane;            // j < CAP (zero-padded boxes -> iou 0)
                float ltx = fmaxf(ax1, sx1[j]), lty = fmaxf(ay1, sy1[j]);
                float rbx = fminf(ax2, sx2[j]), rby = fminf(ay2, sy2[j]);
                float wx = fmaxf(rbx - ltx, 0.f), wy = fmaxf(rby - lty, 0.f);
                float inter = wx * wy;
                float uni = areaA + sar[j] - inter;     // exact ref op order
                float iou = inter / fmaxf(uni, 1e-9f);  // exact IEEE div
                bool sup = (iou > 0.5f) && (j > i);
                unsigned long long bal = __ballot(sup);
                if (lane == 0) {
                    u_mat[rbase + 2 * (w - wb)]     = (unsigned)bal;
                    u_mat[rbase + 2 * (w - wb) + 1] = (unsigned)(bal >> 32);
                }
            }
        }
        __syncthreads();

        // ---- Phase 3c: serial greedy scan — single wave, lane L = removed word L ----
        if (tid < 64) {
            unsigned rem = 0;
            const int Ms = __builtin_amdgcn_readfirstlane(M);
            const int C = (Ms + 31) >> 5;
            for (int c = 0; c < C; ++c) {
                int wb = c >> 1;
                int rl = U32W - 2 * wb;
                int Lc = min(max(tid, 2 * wb), U32W - 1);   // clamp: stray lanes read valid LDS
                int rb0 = ragged_base(wb) + ((c & 1) << 5) * rl + (Lc - 2 * wb);
                unsigned r[32];
#pragma unroll
                for (int t = 0; t < 32; ++t) r[t] = u_mat[rb0 + t * rl];
                unsigned rw = (unsigned)__builtin_amdgcn_readlane((int)rem, c);
                unsigned keepmask = 0;
                int lim = min(32, Ms - (c << 5));
#pragma unroll
                for (int t = 0; t < 32; ++t) {
                    if (t < lim && !((rw >> t) & 1u)) {     // wave-uniform predicate
                        keepmask |= (1u << t);
                        rem |= r[t];
                        rw |= (unsigned)__builtin_amdgcn_readlane((int)r[t], c);
                    }
                }
                if (tid == 0) skmask[c] = keepmask;
            }
        }
        __syncthreads();
        for (int s = tid; s < M; s += NTH)
            if ((skmask[s >> 5] >> (s & 31)) & 1u) skorig[sidx[s]] = 1;
        __syncthreads();
    } else {
        // ---- Fallback (M > CAP, ~never): barrier greedy, boxes recomputed ----
        unsigned char* ssupp = (unsigned char*)u_mat;
        for (int s = tid; s < M; s += NTH) ssupp[s] = 0;
        __syncthreads();
        for (int i = 0; i < M; ++i) {
            __syncthreads();
            if (ssupp[i]) continue;
            int ia = sidx[i];
            float4 pa = ((const float4*)pboxes)[b * QN + ia];
            float ax1 = (pa.x - 0.5f * pa.z) * sw, ay1 = (pa.y - 0.5f * pa.w) * sh;
            float ax2 = (pa.x + 0.5f * pa.z) * sw, ay2 = (pa.y + 0.5f * pa.w) * sh;
            float areaA = fmaxf(ax2 - ax1, 0.f) * fmaxf(ay2 - ay1, 0.f);
            for (int jj = i + 1 + tid; jj < M; jj += NTH) {
                int jb = sidx[jj];
                float4 pq = ((const float4*)pboxes)[b * QN + jb];
                float bx1 = (pq.x - 0.5f * pq.z) * sw, by1 = (pq.y - 0.5f * pq.w) * sh;
                float bx2 = (pq.x + 0.5f * pq.z) * sw, by2 = (pq.y + 0.5f * pq.w) * sh;
                float ltx = fmaxf(ax1, bx1), lty = fmaxf(ay1, by1);
                float rbx = fminf(ax2, bx2), rby = fminf(ay2, by2);
                float wx = fmaxf(rbx - ltx, 0.f), wy = fmaxf(rby - lty, 0.f);
                float inter = wx * wy;
                float areaB = fmaxf(bx2 - bx1, 0.f) * fmaxf(by2 - by1, 0.f);
                float uni = areaA + areaB - inter;
                if (inter / fmaxf(uni, 1e-9f) > 0.5f) ssupp[jj] = 1;
            }
        }
        __syncthreads();
        for (int s = tid; s < M; s += NTH)
            if (!ssupp[s]) skorig[sidx[s]] = 1;
        __syncthreads();
    }

    // ---- Phase 4: write all outputs (d_out poisoned every call) ----
    const long BQ = (long)B * QN;
    for (int q = tid; q < QN; q += NTH) {
        int base = b * QN + q;
        float2 l = ((const float2*)logits)[base];
        float e = expf(fminf(l.x, l.y) - fmaxf(l.x, l.y));
        float score = 1.0f / (1.0f + e);
        float4 pb = ((const float4*)pboxes)[base];
        float x1 = (pb.x - 0.5f * pb.z) * sw, y1 = (pb.y - 0.5f * pb.w) * sh;
        float x2 = (pb.x + 0.5f * pb.z) * sw, y2 = (pb.y + 0.5f * pb.w) * sh;
        int kp = skorig[q];
        out[base] = kp ? score : 0.f;
        out[BQ * 5 + base] = kp ? 1.f : 0.f;
        float4 ob;
        ob.x = kp ? truncf(x1) : 0.f;
        ob.y = kp ? truncf(y1) : 0.f;
        ob.z = kp ? truncf(x2) : 0.f;
        ob.w = kp ? truncf(y2) : 0.f;
        ((float4*)(out + BQ))[base] = ob;
    }
}

extern "C" void kernel_launch(void* const* d_in, const int* in_sizes, int n_in,
                              void* d_out, int out_size, void* d_ws, size_t ws_size,
                              hipStream_t stream) {
    const float* logits = (const float*)d_in[0];
    const float* pboxes = (const float*)d_in[1];
    const int*   img_h  = (const int*)d_in[2];
    const int*   img_w  = (const int*)d_in[3];
    float* out = (float*)d_out;
    const int B = in_sizes[0] / (QN * 2);   // 16

    postprocess_kernel<<<dim3(B), dim3(NTH), 0, stream>>>(
        logits, pboxes, img_h, img_w, out, B);
}

// Round 4
// 135.478 us; speedup vs baseline: 2.3617x; 1.1515x over previous
//
#include <hip/hip_runtime.h>
#include <math.h>

// PostProcess: B=16, Q=2048, C=2.
// scores = max softmax; valid = argmax==0 && score>=0.7; boxes cxcywh->xyxy * (w,h,w,h)
// per-image greedy NMS (IoU>0.5, score-desc stable order) -> keep
// out (f32, concat): scores[B*Q] | boxes[B*Q*4] (trunc int vals) | keep[B*Q]

#define QN   2048
#define NTH  1024
#define CAP  768     // fast-path max valid boxes (E[M]=562, sigma~20)
#define NS   1024    // register-sort capacity (pow2)
#define U32W 24      // u32 words per full matrix row (CAP/32)

__device__ __forceinline__ int ragged_base(int wb) {
    // 64 rows/block; block wb has rows of (U32W - 2*wb) u32 words
    return 64 * wb * (25 - wb);
}

__device__ __forceinline__ unsigned long long shfl_xor_u64(unsigned long long x, int m) {
    int lo = __shfl_xor((int)(unsigned)(x & 0xffffffffull), m, 64);
    int hi = __shfl_xor((int)(unsigned)(x >> 32), m, 64);
    return ((unsigned long long)(unsigned)hi << 32) | (unsigned)lo;
}

// key: ascending sort == score desc, idx asc tiebreak (stable); invalid -> tail.
// NOTE: high word of a VALID key is ~sbits ~ 0xC0xxxxxx (top bit SET) -- validity
// canNOT be read off the key's sign bit (R3 bug). Return it explicitly.
__device__ __forceinline__ unsigned long long score_key(float2 l, int q, bool* valid_out) {
    float mx = fmaxf(l.x, l.y), mn = fminf(l.x, l.y);
    float e = expf(mn - mx);
    float score = 1.0f / (1.0f + e);                 // max softmax prob (exact ref order)
    bool valid = (l.x >= l.y) && (score >= 0.7f);    // argmax tie -> class 0
    *valid_out = valid;
    unsigned sbits = valid ? __float_as_uint(score) : 0u;
    return ((unsigned long long)(~sbits) << 32) | (unsigned)q;
}

__global__ __launch_bounds__(NTH) void postprocess_kernel(
    const float* __restrict__ logits,   // [B,Q,2]
    const float* __restrict__ pboxes,   // [B,Q,4]
    const int* __restrict__ img_h_p,
    const int* __restrict__ img_w_p,
    float* __restrict__ out,
    int B)
{
    // 39936 u32 = 39 KB; aliased: vkey u64[1024] / sort-exchange buf / supp matrix
    __shared__ __align__(16) unsigned int u_mat[9984];
    __shared__ unsigned short sidx[NS];                        // 2 KB sorted->orig
    __shared__ float sx1[CAP], sy1[CAP], sx2[CAP], sy2[CAP], sar[CAP]; // 15 KB SoA
    __shared__ unsigned char skorig[QN];                       // 2 KB keep (orig order)
    __shared__ unsigned int skmask[U32W];                      // keep bits (sorted order)
    __shared__ int sM;

    const int b    = blockIdx.x;
    const int tid  = threadIdx.x;
    const int lane = tid & 63;
    const int wave = tid >> 6;
    const float sw = (float)(*img_w_p);
    const float sh = (float)(*img_h_p);
    unsigned long long* vkey = (unsigned long long*)u_mat;

    if (tid == 0) sM = 0;
    __syncthreads();

    // ---- Phase 1: scores -> compacted valid key list (ballot compaction) ----
    const unsigned long long lmask_lt = (1ull << lane) - 1ull;
#pragma unroll
    for (int qq = 0; qq < 2; ++qq) {
        int q = tid + qq * NTH;
        float2 l = ((const float2*)logits)[b * QN + q];
        bool valid;
        unsigned long long key = score_key(l, q, &valid);
        skorig[q] = 0;
        unsigned long long mb = __ballot(valid);
        int base = 0;
        if (lane == 0 && mb) base = atomicAdd(&sM, __popcll(mb));
        base = __shfl(base, 0, 64);
        if (valid) {
            int slot = base + __popcll(mb & lmask_lt);
            if (slot < NS) vkey[slot] = key;
        }
    }
    __syncthreads();
    const int M = sM;

    if (M <= CAP) {
        // ---- Phase 2: register bitonic sort of NS=1024 u64 (1 elem/thread) ----
        unsigned long long v = (tid < M) ? vkey[tid] : ~0ull;
        __syncthreads();   // vkey region reused as exchange buffer below
        // k = 2..64: all partners in-wave (shfl), no barriers
#pragma unroll
        for (int k = 2; k <= 64; k <<= 1) {
            bool dir = ((tid & k) == 0);
#pragma unroll
            for (int j = k >> 1; j > 0; j >>= 1) {
                unsigned long long o = shfl_xor_u64(v, j);
                bool takeMin = (dir == ((tid & j) == 0));
                bool less = (v < o);
                v = (less == takeMin) ? v : o;
            }
        }
        // k = 128..1024: j>=64 via LDS, j<=32 via shfl
        for (int k = 128; k <= NS; k <<= 1) {
            bool dir = ((tid & k) == 0);
            for (int j = k >> 1; j >= 64; j >>= 1) {
                vkey[tid] = v;
                __syncthreads();
                unsigned long long o = vkey[tid ^ j];
                bool takeMin = (dir == ((tid & j) == 0));
                bool less = (v < o);
                v = (less == takeMin) ? v : o;
                __syncthreads();
            }
#pragma unroll
            for (int j = 32; j > 0; j >>= 1) {
                unsigned long long o = shfl_xor_u64(v, j);
                bool takeMin = (dir == ((tid & j) == 0));
                bool less = (v < o);
                v = (less == takeMin) ? v : o;
            }
        }
        sidx[tid] = (unsigned short)(unsigned)v;
        __syncthreads();

        // ---- Phase 3a: gather sorted boxes (SoA) + areas ----
        if (tid < CAP) {
            int s = tid;
            float x1 = 0.f, y1 = 0.f, x2 = 0.f, y2 = 0.f, ar = 0.f;
            if (s < M) {
                int q = sidx[s];
                float4 pb = ((const float4*)pboxes)[b * QN + q];
                x1 = (pb.x - 0.5f * pb.z) * sw;
                y1 = (pb.y - 0.5f * pb.w) * sh;
                x2 = (pb.x + 0.5f * pb.z) * sw;
                y2 = (pb.y + 0.5f * pb.w) * sh;
                ar = fmaxf(x2 - x1, 0.f) * fmaxf(y2 - y1, 0.f);
            }
            sx1[s] = x1; sy1[s] = y1; sx2[s] = x2; sy2[s] = y2; sar[s] = ar;
        }
        __syncthreads();

        // ---- Phase 3b: suppression bit matrix, 4 rows/wave-group ----
        const int W64 = (M + 63) >> 6;
        for (int g = wave * 4; g < M; g += 64) {       // 4-aligned groups never cross wb
            const int nr = min(4, M - g);
            const int wb = g >> 6;
            const int rl = U32W - 2 * wb;
            float ax1[4], ay1[4], ax2[4], ay2[4], aar[4];
            int rbase[4];
#pragma unroll
            for (int r = 0; r < 4; ++r) {
                int i = g + min(r, nr - 1);            // clamp: stay in-bounds
                ax1[r] = sx1[i]; ay1[r] = sy1[i];      // same-addr broadcast reads
                ax2[r] = sx2[i]; ay2[r] = sy2[i]; aar[r] = sar[i];
                rbase[r] = ragged_base(wb) + ((g + r) & 63) * rl;
            }
            for (int w = wb; w < W64; ++w) {
                int j = (w << 6) | lane;               // j < CAP; padded boxes -> iou 0
                float bx1 = sx1[j], by1 = sy1[j], bx2 = sx2[j], by2 = sy2[j], bar = sar[j];
#pragma unroll
                for (int r = 0; r < 4; ++r) {
                    float ltx = fmaxf(ax1[r], bx1), lty = fmaxf(ay1[r], by1);
                    float rbx = fminf(ax2[r], bx2), rby = fminf(ay2[r], by2);
                    float wx = fmaxf(rbx - ltx, 0.f), wy = fmaxf(rby - lty, 0.f);
                    float inter = wx * wy;
                    float uni = aar[r] + bar - inter;      // exact ref op order
                    float iou = inter / fmaxf(uni, 1e-9f); // exact IEEE div
                    bool sup = (iou > 0.5f) && (j > g + r);
                    unsigned long long bal = __ballot(sup);
                    if (lane == 0 && r < nr) {
                        u_mat[rbase[r] + 2 * (w - wb)]     = (unsigned)bal;
                        u_mat[rbase[r] + 2 * (w - wb) + 1] = (unsigned)(bal >> 32);
                    }
                }
            }
        }
        __syncthreads();

        // ---- Phase 3c: serial greedy scan — single wave, lane L = removed word L ----
        if (tid < 64) {
            unsigned rem = 0;
            const int Ms = __builtin_amdgcn_readfirstlane(M);
            const int C = (Ms + 31) >> 5;
            for (int c = 0; c < C; ++c) {
                int wb = c >> 1;
                int rl = U32W - 2 * wb;
                int Lc = min(max(tid, 2 * wb), U32W - 1);   // clamp strays to valid LDS
                int rb0 = ragged_base(wb) + ((c & 1) << 5) * rl + (Lc - 2 * wb);
                unsigned r[32];
#pragma unroll
                for (int t = 0; t < 32; ++t) r[t] = u_mat[rb0 + t * rl];
                unsigned rw = (unsigned)__builtin_amdgcn_readlane((int)rem, c);
                unsigned keepmask = 0;
                int lim = min(32, Ms - (c << 5));
#pragma unroll
                for (int t = 0; t < 32; ++t) {
                    if (t < lim && !((rw >> t) & 1u)) {     // wave-uniform predicate
                        keepmask |= (1u << t);
                        rem |= r[t];
                        rw |= (unsigned)__builtin_amdgcn_readlane((int)r[t], c);
                    }
                }
                if (tid == 0) skmask[c] = keepmask;
            }
        }
        __syncthreads();
        for (int s = tid; s < M; s += NTH)
            if ((skmask[s >> 5] >> (s & 31)) & 1u) skorig[sidx[s]] = 1;
        __syncthreads();
    } else {
        // ---- Fallback (M > CAP, ~never on bench inputs): full LDS sort + barrier greedy ----
        unsigned long long* skey = (unsigned long long*)u_mat;    // u64[2048] = 16 KB
        unsigned char* ssupp = (unsigned char*)&u_mat[4096];      // 2 KB after keys
        for (int q = tid; q < QN; q += NTH) {
            float2 l = ((const float2*)logits)[b * QN + q];
            bool valid;
            skey[q] = score_key(l, q, &valid);
        }
        __syncthreads();
        for (int k = 2; k <= QN; k <<= 1) {
            for (int j = k >> 1; j > 0; j >>= 1) {
                int i = ((tid & ~(j - 1)) << 1) | (tid & (j - 1));
                int p = i | j;
                bool up = ((i & k) == 0);
                unsigned long long a = skey[i], c2 = skey[p];
                if ((a > c2) == up) { skey[i] = c2; skey[p] = a; }
                __syncthreads();
            }
        }
        for (int s = tid; s < M; s += NTH) ssupp[s] = 0;
        __syncthreads();
        for (int i = 0; i < M; ++i) {
            __syncthreads();
            if (ssupp[i]) continue;
            int ia = (unsigned short)(unsigned)skey[i];
            float4 pa = ((const float4*)pboxes)[b * QN + ia];
            float ax1 = (pa.x - 0.5f * pa.z) * sw, ay1 = (pa.y - 0.5f * pa.w) * sh;
            float ax2 = (pa.x + 0.5f * pa.z) * sw, ay2 = (pa.y + 0.5f * pa.w) * sh;
            float areaA = fmaxf(ax2 - ax1, 0.f) * fmaxf(ay2 - ay1, 0.f);
            for (int jj = i + 1 + tid; jj < M; jj += NTH) {
                int jb = (unsigned short)(unsigned)skey[jj];
                float4 pq = ((const float4*)pboxes)[b * QN + jb];
                float bx1 = (pq.x - 0.5f * pq.z) * sw, by1 = (pq.y - 0.5f * pq.w) * sh;
                float bx2 = (pq.x + 0.5f * pq.z) * sw, by2 = (pq.y + 0.5f * pq.w) * sh;
                float ltx = fmaxf(ax1, bx1), lty = fmaxf(ay1, by1);
                float rbx = fminf(ax2, bx2), rby = fminf(ay2, by2);
                float wx = fmaxf(rbx - ltx, 0.f), wy = fmaxf(rby - lty, 0.f);
                float inter = wx * wy;
                float areaB = fmaxf(bx2 - bx1, 0.f) * fmaxf(by2 - by1, 0.f);
                float uni = areaA + areaB - inter;
                if (inter / fmaxf(uni, 1e-9f) > 0.5f) ssupp[jj] = 1;
            }
        }
        __syncthreads();
        for (int s = tid; s < M; s += NTH)
            if (!ssupp[s]) skorig[(unsigned short)(unsigned)skey[s]] = 1;
        __syncthreads();
    }

    // ---- Phase 4: write all outputs (d_out poisoned every call) ----
    const long BQ = (long)B * QN;
#pragma unroll
    for (int qq = 0; qq < 2; ++qq) {
        int q = tid + qq * NTH;
        int base = b * QN + q;
        float2 l = ((const float2*)logits)[base];
        float e = expf(fminf(l.x, l.y) - fmaxf(l.x, l.y));
        float score = 1.0f / (1.0f + e);
        float4 pb = ((const float4*)pboxes)[base];
        float x1 = (pb.x - 0.5f * pb.z) * sw, y1 = (pb.y - 0.5f * pb.w) * sh;
        float x2 = (pb.x + 0.5f * pb.z) * sw, y2 = (pb.y + 0.5f * pb.w) * sh;
        int kp = skorig[q];
        out[base] = kp ? score : 0.f;
        out[BQ * 5 + base] = kp ? 1.f : 0.f;
        float4 ob;
        ob.x = kp ? truncf(x1) : 0.f;
        ob.y = kp ? truncf(y1) : 0.f;
        ob.z = kp ? truncf(x2) : 0.f;
        ob.w = kp ? truncf(y2) : 0.f;
        ((float4*)(out + BQ))[base] = ob;
    }
}

extern "C" void kernel_launch(void* const* d_in, const int* in_sizes, int n_in,
                              void* d_out, int out_size, void* d_ws, size_t ws_size,
                              hipStream_t stream) {
    const float* logits = (const float*)d_in[0];
    const float* pboxes = (const float*)d_in[1];
    const int*   img_h  = (const int*)d_in[2];
    const int*   img_w  = (const int*)d_in[3];
    float* out = (float*)d_out;
    const int B = in_sizes[0] / (QN * 2);   // 16

    postprocess_kernel<<<dim3(B), dim3(NTH), 0, stream>>>(
        logits, pboxes, img_h, img_w, out, B);
}

// Round 5
// 106.867 us; speedup vs baseline: 2.9940x; 1.2677x over previous
//
#include <hip/hip_runtime.h>
#include <math.h>

// PostProcess: B=16, Q=2048, C=2. Split pipeline:
//  kprep (B blocks):   softmax keys -> ballot compact -> register bitonic sort -> ws
//  kmat  (B*8 blocks): pairwise-IoU suppression bit matrix (ragged) -> ws
//  kfin  (B blocks):   single-wave greedy bitmask scan + scatter + epilogue writes
// ws layout (bytes): M u32[16] @0 | sidx u16[16][1024] @256 | SoA f32[16][5][1024] @33024
//                    | mat u32[16][17408] @360704 | keep u8[16][2048] @1474816  (~1.44 MB)

#define QN   2048
#define NS   1024     // max fast-path valid boxes (E[M]=549, sd 20 -> M>1024 is ~23 sigma)
#define MATW 17408    // ragged u32 words/image = 64 * sum_{wb<16} (32-2wb)

__device__ __forceinline__ int rb32(int wb) { return 64 * wb * (33 - wb); }

__device__ __forceinline__ unsigned long long shfl_xor_u64(unsigned long long x, int m) {
    int lo = __shfl_xor((int)(unsigned)(x & 0xffffffffull), m, 64);
    int hi = __shfl_xor((int)(unsigned)(x >> 32), m, 64);
    return ((unsigned long long)(unsigned)hi << 32) | (unsigned)lo;
}

// ascending sort == score desc, idx asc (stable); invalid -> tail. Validity returned
// explicitly (key's top bit is ~sbits -> SET for valid scores; R3 bug).
__device__ __forceinline__ unsigned long long score_key(float2 l, int q, bool* valid_out) {
    float mx = fmaxf(l.x, l.y), mn = fminf(l.x, l.y);
    float e = expf(mn - mx);
    float score = 1.0f / (1.0f + e);                 // max softmax prob (exact ref order)
    bool valid = (l.x >= l.y) && (score >= 0.7f);    // argmax tie -> class 0
    *valid_out = valid;
    unsigned sbits = valid ? __float_as_uint(score) : 0u;
    return ((unsigned long long)(~sbits) << 32) | (unsigned)q;
}

// ---------------- Kernel 1: compact + sort + SoA to ws ----------------
__global__ __launch_bounds__(1024) void kprep(
    const float* __restrict__ logits, const float* __restrict__ pboxes,
    const int* __restrict__ img_h_p, const int* __restrict__ img_w_p,
    unsigned* __restrict__ wsM, unsigned short* __restrict__ wsidx,
    float* __restrict__ wsoa, unsigned char* __restrict__ wkeep, int B)
{
    __shared__ unsigned long long skey[QN];   // 16 KB; fast path uses [0..NS)
    __shared__ unsigned char ssupp[QN];       // fallback only
    __shared__ int sM;

    const int b = blockIdx.x, tid = threadIdx.x, lane = tid & 63;
    const float sw = (float)(*img_w_p), sh = (float)(*img_h_p);

    if (tid == 0) sM = 0;
    __syncthreads();

    const unsigned long long lmask_lt = (1ull << lane) - 1ull;
#pragma unroll
    for (int qq = 0; qq < 2; ++qq) {
        int q = tid + qq * 1024;
        float2 l = ((const float2*)logits)[b * QN + q];
        bool valid;
        unsigned long long key = score_key(l, q, &valid);
        unsigned long long mb = __ballot(valid);
        int base = 0;
        if (lane == 0 && mb) base = atomicAdd(&sM, __popcll(mb));
        base = __shfl(base, 0, 64);
        if (valid) {
            int slot = base + __popcll(mb & lmask_lt);
            if (slot < NS) skey[slot] = key;
        }
    }
    __syncthreads();
    const int M = sM;

    if (M <= NS) {
        // register bitonic sort of NS u64, 1 elem/thread (verified in R4)
        unsigned long long v = (tid < M) ? skey[tid] : ~0ull;
        __syncthreads();
#pragma unroll
        for (int k = 2; k <= 64; k <<= 1) {
            bool dir = ((tid & k) == 0);
#pragma unroll
            for (int j = k >> 1; j > 0; j >>= 1) {
                unsigned long long o = shfl_xor_u64(v, j);
                bool takeMin = (dir == ((tid & j) == 0));
                v = ((v < o) == takeMin) ? v : o;
            }
        }
        for (int k = 128; k <= NS; k <<= 1) {
            bool dir = ((tid & k) == 0);
            for (int j = k >> 1; j >= 64; j >>= 1) {
                skey[tid] = v;
                __syncthreads();
                unsigned long long o = skey[tid ^ j];
                bool takeMin = (dir == ((tid & j) == 0));
                v = ((v < o) == takeMin) ? v : o;
                __syncthreads();
            }
#pragma unroll
            for (int j = 32; j > 0; j >>= 1) {
                unsigned long long o = shfl_xor_u64(v, j);
                bool takeMin = (dir == ((tid & j) == 0));
                v = ((v < o) == takeMin) ? v : o;
            }
        }
        // write sorted idx + SoA boxes (full NS; padded slots are zeros -> iou 0)
        int qi = (int)((unsigned)v & 0xffffu);
        wsidx[b * NS + tid] = (unsigned short)qi;
        float x1 = 0.f, y1 = 0.f, x2 = 0.f, y2 = 0.f, ar = 0.f;
        if (tid < M) {
            float4 pb = ((const float4*)pboxes)[b * QN + qi];
            x1 = (pb.x - 0.5f * pb.z) * sw;
            y1 = (pb.y - 0.5f * pb.w) * sh;
            x2 = (pb.x + 0.5f * pb.z) * sw;
            y2 = (pb.y + 0.5f * pb.w) * sh;
            ar = fmaxf(x2 - x1, 0.f) * fmaxf(y2 - y1, 0.f);
        }
        float* soa = wsoa + (long)b * 5 * NS;
        soa[tid] = x1; soa[NS + tid] = y1; soa[2 * NS + tid] = x2;
        soa[3 * NS + tid] = y2; soa[4 * NS + tid] = ar;
        if (tid == 0) wsM[b] = (unsigned)M;
    } else {
        // ---- Fallback (M > NS, ~never): full LDS sort + barrier greedy -> wkeep ----
        for (int q = tid; q < QN; q += 1024) {
            float2 l = ((const float2*)logits)[b * QN + q];
            bool valid;
            skey[q] = score_key(l, q, &valid);
            wkeep[b * QN + q] = 0;
        }
        __syncthreads();
        for (int k = 2; k <= QN; k <<= 1)
            for (int j = k >> 1; j > 0; j >>= 1) {
                int i = ((tid & ~(j - 1)) << 1) | (tid & (j - 1));
                int p = i | j;
                bool up = ((i & k) == 0);
                unsigned long long a = skey[i], c2 = skey[p];
                if ((a > c2) == up) { skey[i] = c2; skey[p] = a; }
                __syncthreads();
            }
        for (int s = tid; s < M; s += 1024) ssupp[s] = 0;
        __syncthreads();
        for (int i = 0; i < M; ++i) {
            __syncthreads();
            if (ssupp[i]) continue;
            int ia = (unsigned short)(unsigned)skey[i];
            float4 pa = ((const float4*)pboxes)[b * QN + ia];
            float ax1 = (pa.x - 0.5f * pa.z) * sw, ay1 = (pa.y - 0.5f * pa.w) * sh;
            float ax2 = (pa.x + 0.5f * pa.z) * sw, ay2 = (pa.y + 0.5f * pa.w) * sh;
            float areaA = fmaxf(ax2 - ax1, 0.f) * fmaxf(ay2 - ay1, 0.f);
            for (int jj = i + 1 + tid; jj < M; jj += 1024) {
                int jb = (unsigned short)(unsigned)skey[jj];
                float4 pq = ((const float4*)pboxes)[b * QN + jb];
                float bx1 = (pq.x - 0.5f * pq.z) * sw, by1 = (pq.y - 0.5f * pq.w) * sh;
                float bx2 = (pq.x + 0.5f * pq.z) * sw, by2 = (pq.y + 0.5f * pq.w) * sh;
                float ltx = fmaxf(ax1, bx1), lty = fmaxf(ay1, by1);
                float rbx = fminf(ax2, bx2), rby = fminf(ay2, by2);
                float wx = fmaxf(rbx - ltx, 0.f), wy = fmaxf(rby - lty, 0.f);
                float inter = wx * wy;
                float areaB = fmaxf(bx2 - bx1, 0.f) * fmaxf(by2 - by1, 0.f);
                float uni = areaA + areaB - inter;
                if (inter / fmaxf(uni, 1e-9f) > 0.5f) ssupp[jj] = 1;
            }
        }
        __syncthreads();
        for (int s = tid; s < M; s += 1024)
            if (!ssupp[s]) wkeep[b * QN + (unsigned short)(unsigned)skey[s]] = 1;
        if (tid == 0) wsM[b] = (unsigned)M;
    }
}

// ---------------- Kernel 2: suppression bit matrix (8 block-slices/image) ----------------
__global__ __launch_bounds__(1024) void kmat(
    const unsigned* __restrict__ wsM, const float* __restrict__ wsoa,
    unsigned* __restrict__ wmat, int B)
{
    const int b = blockIdx.x % B, slice = blockIdx.x / B;
    const int tid = threadIdx.x, wave = tid >> 6, lane = tid & 63;
    const int M = (int)wsM[b];
    if (M > NS) return;

    __shared__ float sx1[NS], sy1[NS], sx2[NS], sy2[NS], sar[NS];   // 20 KB
    const float* soa = wsoa + (long)b * 5 * NS;
    sx1[tid] = soa[tid];          sy1[tid] = soa[NS + tid];
    sx2[tid] = soa[2 * NS + tid]; sy2[tid] = soa[3 * NS + tid];
    sar[tid] = soa[4 * NS + tid];
    __syncthreads();

    unsigned* mat = wmat + (long)b * MATW;
    const int NG = (M + 3) >> 2;
    const int W64 = (M + 63) >> 6;
    for (int gi = slice * 16 + wave; gi < NG; gi += 128) {
        const int g = gi << 2;
        const int nr = min(4, M - g);
        const int wb = g >> 6;
        const int rl = 32 - 2 * wb;
        float ax1[4], ay1[4], ax2[4], ay2[4], aar[4];
        int rbase[4];
#pragma unroll
        for (int r = 0; r < 4; ++r) {
            int i = g + min(r, nr - 1);
            ax1[r] = sx1[i]; ay1[r] = sy1[i];
            ax2[r] = sx2[i]; ay2[r] = sy2[i]; aar[r] = sar[i];
            rbase[r] = rb32(wb) + ((g + r) & 63) * rl;
        }
        for (int w = wb; w < W64; ++w) {
            int j = (w << 6) | lane;
            float bx1 = sx1[j], by1 = sy1[j], bx2 = sx2[j], by2 = sy2[j], bar = sar[j];
#pragma unroll
            for (int r = 0; r < 4; ++r) {
                float ltx = fmaxf(ax1[r], bx1), lty = fmaxf(ay1[r], by1);
                float rbx = fminf(ax2[r], bx2), rby = fminf(ay2[r], by2);
                float wx = fmaxf(rbx - ltx, 0.f), wy = fmaxf(rby - lty, 0.f);
                float inter = wx * wy;
                float uni = aar[r] + bar - inter;       // exact ref op order
                float iou = inter / fmaxf(uni, 1e-9f);  // exact IEEE div
                bool sup = (iou > 0.5f) && (j > g + r);
                unsigned long long bal = __ballot(sup);
                if (lane == 0 && r < nr)
                    *(unsigned long long*)(mat + rbase[r] + 2 * (w - wb)) = bal;
            }
        }
    }
}

// ---------------- Kernel 3: greedy scan + scatter + epilogue ----------------
__global__ __launch_bounds__(1024) void kfin(
    const float* __restrict__ logits, const float* __restrict__ pboxes,
    const int* __restrict__ img_h_p, const int* __restrict__ img_w_p,
    const unsigned* __restrict__ wsM, const unsigned short* __restrict__ wsidx,
    const unsigned* __restrict__ wmat, const unsigned char* __restrict__ wkeep,
    float* __restrict__ out, int B)
{
    __shared__ unsigned char keepq[QN];   // keep flags, orig order
    __shared__ unsigned skm[32];          // keep bits, sorted order

    const int b = blockIdx.x, tid = threadIdx.x;
    const float sw = (float)(*img_w_p), sh = (float)(*img_h_p);
    const int M = (int)wsM[b];

    if (M <= NS) {
        keepq[tid] = 0; keepq[tid + 1024] = 0;
        if (tid < 64) {
            if (tid < 32) skm[tid] = 0;           // in-wave order before scan writes
            const unsigned* gm = wmat + (long)b * MATW;
            unsigned rem = 0;
            const int Ms = __builtin_amdgcn_readfirstlane(M);
            const int C = (Ms + 31) >> 5;
            unsigned rcur[32], rnxt[32];
            if (C > 0) {
                int wb = 0, rl = 32;
                int Lc = min(tid, 31);
                int rb0 = ((0 & 1) << 5) * rl + Lc;   // rb32(0)=0
#pragma unroll
                for (int t = 0; t < 32; ++t) rcur[t] = gm[rb0 + t * rl];
            }
            for (int c = 0; c < C; ++c) {
                if (c + 1 < C) {                      // prefetch next chunk
                    int cn = c + 1, wbn = cn >> 1, rln = 32 - 2 * wbn;
                    int Lcn = min(max(tid, 2 * wbn), 31);
                    int rb0n = rb32(wbn) + ((cn & 1) << 5) * rln + (Lcn - 2 * wbn);
#pragma unroll
                    for (int t = 0; t < 32; ++t) rnxt[t] = gm[rb0n + t * rln];
                }
                unsigned rw = (unsigned)__builtin_amdgcn_readlane((int)rem, c);
                unsigned keepmask = 0;
                int lim = min(32, Ms - (c << 5));
#pragma unroll
                for (int t = 0; t < 32; ++t) {
                    if (t < lim && !((rw >> t) & 1u)) {   // wave-uniform predicate
                        keepmask |= (1u << t);
                        rem |= rcur[t];
                        rw |= (unsigned)__builtin_amdgcn_readlane((int)rcur[t], c);
                    }
                }
                if (tid == 0) skm[c] = keepmask;
                if (c + 1 < C) {
#pragma unroll
                    for (int t = 0; t < 32; ++t) rcur[t] = rnxt[t];
                }
            }
        }
        __syncthreads();
        for (int s = tid; s < M; s += 1024)
            if ((skm[s >> 5] >> (s & 31)) & 1u) keepq[wsidx[b * NS + s]] = 1;
        __syncthreads();
    } else {
        keepq[tid] = wkeep[b * QN + tid];
        keepq[tid + 1024] = wkeep[b * QN + tid + 1024];
        __syncthreads();
    }

    // epilogue: all outputs (d_out poisoned every call)
    const long BQ = (long)B * QN;
#pragma unroll
    for (int qq = 0; qq < 2; ++qq) {
        int q = tid + qq * 1024;
        int base = b * QN + q;
        float2 l = ((const float2*)logits)[base];
        float e = expf(fminf(l.x, l.y) - fmaxf(l.x, l.y));
        float score = 1.0f / (1.0f + e);
        float4 pb = ((const float4*)pboxes)[base];
        float x1 = (pb.x - 0.5f * pb.z) * sw, y1 = (pb.y - 0.5f * pb.w) * sh;
        float x2 = (pb.x + 0.5f * pb.z) * sw, y2 = (pb.y + 0.5f * pb.w) * sh;
        int kp = keepq[q];
        out[base] = kp ? score : 0.f;
        out[BQ * 5 + base] = kp ? 1.f : 0.f;
        float4 ob;
        ob.x = kp ? truncf(x1) : 0.f;
        ob.y = kp ? truncf(y1) : 0.f;
        ob.z = kp ? truncf(x2) : 0.f;
        ob.w = kp ? truncf(y2) : 0.f;
        ((float4*)(out + BQ))[base] = ob;
    }
}

extern "C" void kernel_launch(void* const* d_in, const int* in_sizes, int n_in,
                              void* d_out, int out_size, void* d_ws, size_t ws_size,
                              hipStream_t stream) {
    const float* logits = (const float*)d_in[0];
    const float* pboxes = (const float*)d_in[1];
    const int*   img_h  = (const int*)d_in[2];
    const int*   img_w  = (const int*)d_in[3];
    float* out = (float*)d_out;
    const int B = in_sizes[0] / (QN * 2);   // 16

    char* ws = (char*)d_ws;                          // needs ~1.44 MB
    unsigned*       wsM   = (unsigned*)(ws + 0);
    unsigned short* wsidx = (unsigned short*)(ws + 256);
    float*          wsoa  = (float*)(ws + 33024);
    unsigned*       wmat  = (unsigned*)(ws + 360704);
    unsigned char*  wkeep = (unsigned char*)(ws + 1474816);

    kprep<<<dim3(B), dim3(1024), 0, stream>>>(logits, pboxes, img_h, img_w,
                                              wsM, wsidx, wsoa, wkeep, B);
    kmat<<<dim3(B * 8), dim3(1024), 0, stream>>>(wsM, wsoa, wmat, B);
    kfin<<<dim3(B), dim3(1024), 0, stream>>>(logits, pboxes, img_h, img_w,
                                             wsM, wsidx, wmat, wkeep, out, B);
}